// Round 14
// baseline (118.033 us; speedup 1.0000x reference)
//
#include <hip/hip_runtime.h>

typedef __attribute__((ext_vector_type(8))) short short8;
typedef __attribute__((ext_vector_type(4))) float f32x4;

__device__ inline float bf2f(unsigned short u) {
    return __uint_as_float(((unsigned int)u) << 16);
}
__device__ inline unsigned short f2bf(float f) {
    unsigned int x = __float_as_uint(f);
    return (unsigned short)((x + 0x7fffu + ((x >> 16) & 1u)) >> 16);
}

template<bool F32>
__device__ inline short8 load8(const void* p, long i) {  // i % 8 == 0 at all call sites
    short8 r;
    if (F32) {
        const float* fp = (const float*)p + i;
        f32x4 a = *(const f32x4*)fp;
        f32x4 b = *(const f32x4*)(fp + 4);
#pragma unroll
        for (int j = 0; j < 4; ++j) { r[j] = (short)f2bf(a[j]); r[4 + j] = (short)f2bf(b[j]); }
    } else {
        r = *(const short8*)((const unsigned short*)p + i);
    }
    return r;
}

// ---------------- K1: fully-fused Q-proj + KV-proj + attention, grid (64 graphs, 8 heads) ----
// All inputs fp32, converted in-register / in-staging. XCD swizzle: id = g + 64h -> id%8 = g%8,
// all 8 heads of a graph share one XCD's L2 (x slice fetched once per graph).
// LDS arena (66048 B): Q[32][72] | K[128][72] | Vt[64][136] | P[32][136] | union{Wstage[16][512], S[32][132]}
// (S aliases Wstage: Wstage's last read is in the KV-proj MFMAs, S is written only after that.)
__global__ __launch_bounds__(256, 2) void kvattn_full_kernel(
    const float* __restrict__ x,      // (8192,512) fp32
    const float* __restrict__ w_in,   // (1536,512) fp32
    const float* __restrict__ b_in,   // (1536) fp32
    const float* __restrict__ aggrs,  // (32,512) fp32
    unsigned short* __restrict__ Oh)  // (8,2048,64) bf16
{
    const int g = blockIdx.x;  // 0..63  (fast dim -> XCD id = g%8)
    const int h = blockIdx.y;  // 0..7
    const int tid = threadIdx.x;
    const int w = tid >> 6, lane = tid & 63, l15 = lane & 15, l4 = lane >> 4;

    __shared__ __align__(16) unsigned char arena[66048];
    unsigned short (*Q_lds)[72]    = (unsigned short(*)[72])(arena);            // 4608
    unsigned short (*K_lds)[72]    = (unsigned short(*)[72])(arena + 4608);     // 18432
    unsigned short (*Vt_lds)[136]  = (unsigned short(*)[136])(arena + 23040);   // 17408
    unsigned short (*P_lds)[136]   = (unsigned short(*)[136])(arena + 40448);   // 8704
    unsigned short (*Wstage)[512]  = (unsigned short(*)[512])(arena + 49152);   // 16384
    float          (*S_lds)[132]   = (float(*)[132])(arena + 49152);            // 16896 (aliases Wstage)

    // ---- Phase 0: Q_h = aggrs @ Wq_h^T + bq (32x64); wave w owns cols d0=w*16 ----
    // (R5-proven attn_body<true> phase; fp32 loads inline)
    {
        const int d0 = w * 16;
        const float bq = b_in[h * 64 + d0 + l15];
        for (int rt = 0; rt < 2; ++rt) {
            f32x4 acc = {0.f, 0.f, 0.f, 0.f};
#pragma unroll
            for (int kk = 0; kk < 16; ++kk) {
                short8 a = load8<true>(aggrs, (long)(rt * 16 + l15) * 512 + kk * 32 + l4 * 8);
                short8 b = load8<true>(w_in, (long)(h * 64 + d0 + l15) * 512 + kk * 32 + l4 * 8);
                acc = __builtin_amdgcn_mfma_f32_16x16x32_bf16(a, b, acc, 0, 0, 0);
            }
#pragma unroll
            for (int r = 0; r < 4; ++r)
                Q_lds[rt * 16 + l4 * 4 + r][d0 + l15] = f2bf(acc[r] + bq);
        }
    }
    // (no sync needed: Q_lds first read after the KV-proj __syncthreads chain)

    // ---- x A-fragments: wave w owns nodes w*32..w*32+31, fp32 -> bf16 in regs ----
    short8 a0[16], a1[16];
    {
        const long xrow0 = (long)(g * 128 + w * 32 + l15) * 512 + l4 * 8;
#pragma unroll
        for (int kk = 0; kk < 16; ++kk) a0[kk] = load8<true>(x, xrow0 + kk * 32);
        const long xrow1 = xrow0 + 16 * 512;
#pragma unroll
        for (int kk = 0; kk < 16; ++kk) a1[kk] = load8<true>(x, xrow1 + kk * 32);
    }

    // ---- KV projection: 8 chunks of 16 weight rows (0..3 = K cols, 4..7 = V cols) ----
    for (int cb = 0; cb < 8; ++cb) {
        if (cb) __syncthreads();
        const int wrow = (cb < 4) ? (h * 64 + cb * 16) : (512 + h * 64 + (cb - 4) * 16);
        // stage 16 rows swizzled, fp32 -> bf16 inline
#pragma unroll
        for (int j = 0; j < 4; ++j) {
            int c = tid + j * 256;        // 0..1023
            int row = c >> 6;             // 0..15
            int col8 = c & 63;            // 16B unit
            *(short8*)(&Wstage[row][(col8 ^ (row & 7)) * 8]) =
                load8<true>(w_in, (long)(512 + wrow + row) * 512 + col8 * 8);
        }
        __syncthreads();
        const float bias = b_in[512 + wrow + l15];
#pragma unroll
        for (int rt = 0; rt < 2; ++rt) {
            f32x4 acc = {0.f, 0.f, 0.f, 0.f};
#pragma unroll
            for (int kk = 0; kk < 16; ++kk) {
                short8 b = *(const short8*)(&Wstage[l15][((kk * 4 + l4) ^ (l15 & 7)) * 8]);
                acc = __builtin_amdgcn_mfma_f32_16x16x32_bf16(rt ? a1[kk] : a0[kk], b, acc, 0, 0, 0);
            }
            const int node0 = w * 32 + rt * 16 + l4 * 4;
            if (cb < 4) {
                const int col = cb * 16 + l15;
#pragma unroll
                for (int r = 0; r < 4; ++r) K_lds[node0 + r][col] = f2bf(acc[r] + bias);
            } else {
                const int d = (cb - 4) * 16 + l15;
#pragma unroll
                for (int r = 0; r < 4; ++r) Vt_lds[d][node0 + r] = f2bf(acc[r] + bias);
            }
        }
    }
    __syncthreads();   // Wstage dead from here; S_lds may now use its space

    // ---- S = (Q_h @ K_h^T) * 0.125 ----
    for (int lt = 0; lt < 2; ++lt) {
        const int l0 = lt * 16;
        short8 qa[2];
        qa[0] = *(const short8*)(&Q_lds[l0 + l15][l4 * 8]);
        qa[1] = *(const short8*)(&Q_lds[l0 + l15][32 + l4 * 8]);
        for (int ct = 0; ct < 2; ++ct) {
            const int n0 = w * 32 + ct * 16;
            f32x4 acc = {0.f, 0.f, 0.f, 0.f};
#pragma unroll
            for (int kk = 0; kk < 2; ++kk) {
                short8 b = *(const short8*)(&K_lds[n0 + l15][kk * 32 + l4 * 8]);
                acc = __builtin_amdgcn_mfma_f32_16x16x32_bf16(qa[kk], b, acc, 0, 0, 0);
            }
#pragma unroll
            for (int r = 0; r < 4; ++r)
                S_lds[l0 + l4 * 4 + r][n0 + l15] = acc[r] * 0.125f;
        }
    }
    __syncthreads();

    // ---- row softmax over 128 nodes ----
    {
        const int row = tid >> 3;
        const int j = tid & 7;
        float vals[16];
        float m = -1e30f;
#pragma unroll
        for (int c = 0; c < 16; ++c) {
            vals[c] = S_lds[row][j + c * 8];
            m = fmaxf(m, vals[c]);
        }
#pragma unroll
        for (int s = 1; s < 8; s <<= 1) m = fmaxf(m, __shfl_xor(m, s));
        float sum = 0.f;
#pragma unroll
        for (int c = 0; c < 16; ++c) {
            vals[c] = __expf(vals[c] - m);
            sum += vals[c];
        }
#pragma unroll
        for (int s = 1; s < 8; s <<= 1) sum += __shfl_xor(sum, s);
        const float inv = 1.0f / sum;
#pragma unroll
        for (int c = 0; c < 16; ++c)
            P_lds[row][j + c * 8] = f2bf(vals[c] * inv);
    }
    __syncthreads();

    // ---- O_h = P @ V_h -> Oh[h][g*32+l][d] ----
    for (int lt = 0; lt < 2; ++lt) {
        const int l0 = lt * 16;
        const int d0 = w * 16;
        f32x4 acc = {0.f, 0.f, 0.f, 0.f};
#pragma unroll
        for (int kk = 0; kk < 4; ++kk) {
            short8 a = *(const short8*)(&P_lds[l0 + l15][kk * 32 + l4 * 8]);
            short8 b = *(const short8*)(&Vt_lds[d0 + l15][kk * 32 + l4 * 8]);
            acc = __builtin_amdgcn_mfma_f32_16x16x32_bf16(a, b, acc, 0, 0, 0);
        }
#pragma unroll
        for (int r = 0; r < 4; ++r) {
            const int l = l0 + l4 * 4 + r;
            Oh[(long)h * 131072 + (long)(g * 32 + l) * 64 + d0 + l15] = f2bf(acc[r]);
        }
    }
}

// ---------------- K2: out = Oh-gathered @ Wo^T(fp32) + bo, grid 128 ----------------
__global__ __launch_bounds__(256, 2) void outproj2f_kernel(
    const unsigned short* __restrict__ Oh, const float* __restrict__ Wo,
    const float* __restrict__ bo, float* __restrict__ out)
{
    const int by = blockIdx.x;  // 0..127 (16 rows each)
    const int tid = threadIdx.x;
    const int w = tid >> 6, lane = tid & 63, l15 = lane & 15, l4 = lane >> 4;

    __shared__ __align__(16) unsigned short O_lds[16][520];

#pragma unroll
    for (int i = 0; i < 4; ++i) {
        int c2 = tid + i * 256;       // 16 rows x 64 chunks of 8
        int row = c2 >> 6;
        int c = c2 & 63;
        int hh = c >> 3;
        int d = (c & 7) * 8;
        *(short8*)(&O_lds[row][c * 8]) =
            *(const short8*)(Oh + (long)hh * 131072 + (long)(by * 16 + row) * 64 + d);
    }
    __syncthreads();

    short8 a[16];
#pragma unroll
    for (int kk = 0; kk < 16; ++kk)
        a[kk] = *(const short8*)(&O_lds[l15][kk * 32 + l4 * 8]);

    const int cbase = w * 128;
    for (int ct = 0; ct < 8; ++ct) {
        const int col0 = cbase + ct * 16;
        f32x4 acc = {0.f, 0.f, 0.f, 0.f};
#pragma unroll
        for (int kk = 0; kk < 16; ++kk) {
            short8 b = load8<true>(Wo, (long)(col0 + l15) * 512 + kk * 32 + l4 * 8);
            acc = __builtin_amdgcn_mfma_f32_16x16x32_bf16(a[kk], b, acc, 0, 0, 0);
        }
        const float bias = bo[col0 + l15];
#pragma unroll
        for (int r = 0; r < 4; ++r)
            out[(long)(by * 16 + l4 * 4 + r) * 512 + col0 + l15] = acc[r] + bias;
    }
}

// ================= fp32 fallback (tiny ws) =================
template<bool F32>
__device__ void attn_body(const void* x, const void* w_in, const float* b_in,
                          const void* aggrs, float* O) {
    const int h = blockIdx.x;
    const int g = blockIdx.y;
    const int tid = threadIdx.x;
    const int w = tid >> 6, lane = tid & 63, l15 = lane & 15, l4 = lane >> 4;

    __shared__ __align__(16) unsigned short Q_lds[32][72];
    __shared__ __align__(16) unsigned short K_lds[128][72];
    __shared__ __align__(16) unsigned short Vt_lds[64][136];
    __shared__ __align__(16) float S_lds[32][132];
    __shared__ __align__(16) unsigned short P_lds[32][136];

    const long xg = (long)g * 128 * 512;
    const long WqO = (long)(h * 64) * 512;
    const long WkO = (long)(512 + h * 64) * 512;
    const long WvO = (long)(1024 + h * 64) * 512;

    {
        const int d0 = w * 16;
        const float bq = b_in[h * 64 + d0 + l15];
        for (int rt = 0; rt < 2; ++rt) {
            f32x4 acc = {0.f, 0.f, 0.f, 0.f};
#pragma unroll
            for (int kk = 0; kk < 16; ++kk) {
                short8 a = load8<F32>(aggrs, (long)(rt * 16 + l15) * 512 + l4 * 8 + kk * 32);
                short8 b = load8<F32>(w_in, WqO + (long)(d0 + l15) * 512 + l4 * 8 + kk * 32);
                acc = __builtin_amdgcn_mfma_f32_16x16x32_bf16(a, b, acc, 0, 0, 0);
            }
#pragma unroll
            for (int r = 0; r < 4; ++r)
                Q_lds[rt * 16 + l4 * 4 + r][d0 + l15] = f2bf(acc[r] + bq);
        }
    }
    for (int rt = 0; rt < 2; ++rt) {
        const int n0 = w * 32 + rt * 16;
        short8 a[16];
#pragma unroll
        for (int kk = 0; kk < 16; ++kk)
            a[kk] = load8<F32>(x, xg + (long)(n0 + l15) * 512 + l4 * 8 + kk * 32);
        for (int ct = 0; ct < 4; ++ct) {
            const int d0 = ct * 16;
            f32x4 accK = {0.f, 0.f, 0.f, 0.f};
            f32x4 accV = {0.f, 0.f, 0.f, 0.f};
#pragma unroll
            for (int kk = 0; kk < 16; ++kk) {
                short8 bk = load8<F32>(w_in, WkO + (long)(d0 + l15) * 512 + l4 * 8 + kk * 32);
                short8 bv = load8<F32>(w_in, WvO + (long)(d0 + l15) * 512 + l4 * 8 + kk * 32);
                accK = __builtin_amdgcn_mfma_f32_16x16x32_bf16(a[kk], bk, accK, 0, 0, 0);
                accV = __builtin_amdgcn_mfma_f32_16x16x32_bf16(a[kk], bv, accV, 0, 0, 0);
            }
            const float biasK = b_in[512 + h * 64 + d0 + l15];
            const float biasV = b_in[1024 + h * 64 + d0 + l15];
#pragma unroll
            for (int r = 0; r < 4; ++r) {
                const int row = n0 + l4 * 4 + r;
                const int col = d0 + l15;
                K_lds[row][col] = f2bf(accK[r] + biasK);
                Vt_lds[col][row] = f2bf(accV[r] + biasV);
            }
        }
    }
    __syncthreads();
    for (int lt = 0; lt < 2; ++lt) {
        const int l0 = lt * 16;
        short8 qa[2];
        qa[0] = *(const short8*)(&Q_lds[l0 + l15][l4 * 8]);
        qa[1] = *(const short8*)(&Q_lds[l0 + l15][32 + l4 * 8]);
        for (int ct = 0; ct < 2; ++ct) {
            const int n0 = w * 32 + ct * 16;
            f32x4 acc = {0.f, 0.f, 0.f, 0.f};
#pragma unroll
            for (int kk = 0; kk < 2; ++kk) {
                short8 b = *(const short8*)(&K_lds[n0 + l15][kk * 32 + l4 * 8]);
                acc = __builtin_amdgcn_mfma_f32_16x16x32_bf16(qa[kk], b, acc, 0, 0, 0);
            }
#pragma unroll
            for (int r = 0; r < 4; ++r)
                S_lds[l0 + l4 * 4 + r][n0 + l15] = acc[r] * 0.125f;
        }
    }
    __syncthreads();
    {
        const int row = tid >> 3;
        const int j = tid & 7;
        float vals[16];
        float m = -1e30f;
#pragma unroll
        for (int c = 0; c < 16; ++c) {
            vals[c] = S_lds[row][j + c * 8];
            m = fmaxf(m, vals[c]);
        }
#pragma unroll
        for (int s = 1; s < 8; s <<= 1) m = fmaxf(m, __shfl_xor(m, s));
        float sum = 0.f;
#pragma unroll
        for (int c = 0; c < 16; ++c) {
            vals[c] = __expf(vals[c] - m);
            sum += vals[c];
        }
#pragma unroll
        for (int s = 1; s < 8; s <<= 1) sum += __shfl_xor(sum, s);
        const float inv = 1.0f / sum;
#pragma unroll
        for (int c = 0; c < 16; ++c)
            P_lds[row][j + c * 8] = f2bf(vals[c] * inv);
    }
    __syncthreads();
    for (int lt = 0; lt < 2; ++lt) {
        const int l0 = lt * 16;
        const int d0 = w * 16;
        f32x4 acc = {0.f, 0.f, 0.f, 0.f};
#pragma unroll
        for (int kk = 0; kk < 4; ++kk) {
            short8 a = *(const short8*)(&P_lds[l0 + l15][kk * 32 + l4 * 8]);
            short8 b = *(const short8*)(&Vt_lds[d0 + l15][kk * 32 + l4 * 8]);
            acc = __builtin_amdgcn_mfma_f32_16x16x32_bf16(a, b, acc, 0, 0, 0);
        }
#pragma unroll
        for (int r = 0; r < 4; ++r) {
            const int l = l0 + l4 * 4 + r;
            O[(long)(g * 32 + l) * 512 + h * 64 + d0 + l15] = acc[r];
        }
    }
}
__global__ __launch_bounds__(256) void attn_f32(const float* x, const float* w_in,
                                                const float* b_in, const float* aggrs,
                                                float* O) {
    attn_body<true>(x, w_in, b_in, aggrs, O);
}

template<bool F32>
__device__ void outproj_body(float* Out, const void* Wo, const float* bo) {
    const int by = blockIdx.x;
    const int tid = threadIdx.x;
    const int w = tid >> 6, lane = tid & 63, l15 = lane & 15, l4 = lane >> 4;

    __shared__ __align__(16) unsigned short O_lds[16][520];

#pragma unroll
    for (int i = 0; i < 4; ++i) {
        int c2 = tid + i * 256;
        int row = c2 >> 6;
        int col = (c2 & 63) * 8;
        const float* src = Out + (long)(by * 16 + row) * 512 + col;
        f32x4 a = *(const f32x4*)src;
        f32x4 b = *(const f32x4*)(src + 4);
        short8 v;
#pragma unroll
        for (int j = 0; j < 4; ++j) { v[j] = (short)f2bf(a[j]); v[4 + j] = (short)f2bf(b[j]); }
        *(short8*)(&O_lds[row][col]) = v;
    }
    __syncthreads();

    short8 a[16];
#pragma unroll
    for (int kk = 0; kk < 16; ++kk)
        a[kk] = *(const short8*)(&O_lds[l15][kk * 32 + l4 * 8]);

    const int cbase = w * 128;
    for (int ct = 0; ct < 8; ++ct) {
        const int col0 = cbase + ct * 16;
        f32x4 acc = {0.f, 0.f, 0.f, 0.f};
#pragma unroll
        for (int kk = 0; kk < 16; ++kk) {
            short8 b = load8<F32>(Wo, (long)(col0 + l15) * 512 + l4 * 8 + kk * 32);
            acc = __builtin_amdgcn_mfma_f32_16x16x32_bf16(a[kk], b, acc, 0, 0, 0);
        }
        const float bias = bo[col0 + l15];
#pragma unroll
        for (int r = 0; r < 4; ++r)
            Out[(long)(by * 16 + l4 * 4 + r) * 512 + col0 + l15] = acc[r] + bias;
    }
}
__global__ __launch_bounds__(256) void outproj_f32(float* Out, const float* Wo,
                                                   const float* bo) {
    outproj_body<true>(Out, Wo, bo);
}

extern "C" void kernel_launch(void* const* d_in, const int* in_sizes, int n_in,
                              void* d_out, int out_size, void* d_ws, size_t ws_size,
                              hipStream_t stream) {
    // Size-based input dispatch — all 7 element counts distinct -> robust to any ordering.
    const int want[7] = {64 * 128 * 512, 64 * 128, 32 * 512, 1536 * 512, 1536, 512 * 512, 512};
    const void* p[7] = {0, 0, 0, 0, 0, 0, 0};
    for (int i = 0; i < n_in && i < 16; ++i)
        for (int j = 0; j < 7; ++j)
            if (in_sizes[i] == want[j] && p[j] == 0) { p[j] = d_in[i]; break; }

    const float* x     = (const float*)p[0];
    const float* aggrs = (const float*)p[2];
    const float* w_in  = (const float*)p[3];
    const float* b_in  = (const float*)p[4];
    const float* Wo    = (const float*)p[5];
    const float* bo    = (const float*)p[6];
    float* out = (float*)d_out;  // (2048,512) fp32

    // ws: Oh (8,2048,64) bf16 = 2 MB
    unsigned short* Oh = (unsigned short*)d_ws;
    if (ws_size >= (size_t)8 * 2048 * 64 * 2) {
        kvattn_full_kernel<<<dim3(64, 8), dim3(256), 0, stream>>>(x, w_in, b_in, aggrs, Oh);
        outproj2f_kernel<<<dim3(128), dim3(256), 0, stream>>>(Oh, Wo, bo, out);
    } else {
        attn_f32<<<dim3(8, 64), dim3(256), 0, stream>>>(x, w_in, b_in, aggrs, out);
        outproj_f32<<<dim3(128), dim3(256), 0, stream>>>(out, Wo, bo);
    }
}

// Round 15
// 55.890 us; speedup vs baseline: 2.1119x; 2.1119x over previous
//
#include <hip/hip_runtime.h>

typedef __attribute__((ext_vector_type(8))) short short8;
typedef __attribute__((ext_vector_type(4))) float f32x4;

__device__ inline float bf2f(unsigned short u) {
    return __uint_as_float(((unsigned int)u) << 16);
}
__device__ inline unsigned short f2bf(float f) {
    unsigned int x = __float_as_uint(f);
    return (unsigned short)((x + 0x7fffu + ((x >> 16) & 1u)) >> 16);
}

template<bool F32>
__device__ inline short8 load8(const void* p, long i) {  // i % 8 == 0 at all call sites
    short8 r;
    if (F32) {
        const float* fp = (const float*)p + i;
        f32x4 a = *(const f32x4*)fp;
        f32x4 b = *(const f32x4*)(fp + 4);
#pragma unroll
        for (int j = 0; j < 4; ++j) { r[j] = (short)f2bf(a[j]); r[4 + j] = (short)f2bf(b[j]); }
    } else {
        r = *(const short8*)((const unsigned short*)p + i);
    }
    return r;
}

// ---------------- K1: prep = Q-projection + bf16 conversion of wkv/wob/x ----------------
__global__ __launch_bounds__(256) void prep_kernel(
    const float* __restrict__ w_in, const float* __restrict__ Wo,
    const float* __restrict__ aggrs, const float* __restrict__ b_in,
    const float* __restrict__ x,
    unsigned short* __restrict__ wkv,   // (1024,512) bf16 (in_proj_w rows 512..1536)
    unsigned short* __restrict__ wob,   // (512,512) bf16
    unsigned short* __restrict__ Qs,    // (32,512) bf16
    unsigned short* __restrict__ xb)    // (8192,512) bf16
{
    if (blockIdx.x < 8) {
        const int tid = threadIdx.x;
        const int w = tid >> 6, lane = tid & 63, l15 = lane & 15, l4 = lane >> 4;
        const int col0 = blockIdx.x * 64 + w * 16;
        const float bq = b_in[col0 + l15];
        for (int rt = 0; rt < 2; ++rt) {
            f32x4 acc = {0.f, 0.f, 0.f, 0.f};
#pragma unroll
            for (int kk = 0; kk < 16; ++kk) {
                short8 a = load8<true>(aggrs, (long)(rt * 16 + l15) * 512 + kk * 32 + l4 * 8);
                short8 b = load8<true>(w_in, (long)(col0 + l15) * 512 + kk * 32 + l4 * 8);
                acc = __builtin_amdgcn_mfma_f32_16x16x32_bf16(a, b, acc, 0, 0, 0);
            }
#pragma unroll
            for (int r = 0; r < 4; ++r)
                Qs[(long)(rt * 16 + l4 * 4 + r) * 512 + col0 + l15] = f2bf(acc[r] + bq);
        }
        return;
    }
    long u = (long)(blockIdx.x - 8) * 256 + threadIdx.x;  // units of 8 elems
    const float* src;
    unsigned short* dst;
    long base;
    if (u < 65536)        { src = w_in + (long)512 * 512; dst = wkv; base = u; }
    else if (u < 98304)   { src = Wo;  dst = wob; base = u - 65536; }
    else if (u < 622592)  { src = x;   dst = xb;  base = u - 98304; }
    else return;
    long i = base * 8;
    f32x4 a = *(const f32x4*)(src + i);
    f32x4 b = *(const f32x4*)(src + i + 4);
    short8 v;
#pragma unroll
    for (int j = 0; j < 4; ++j) { v[j] = (short)f2bf(a[j]); v[4 + j] = (short)f2bf(b[j]); }
    *(short8*)(dst + i) = v;
}

// ---------------- K2: fused KV-projection + attention, grid (64 graphs, 8 heads) ----------------
// XCD swizzle: linear block id = g + 64*h -> id%8 = g%8, so all 8 heads of a graph
// share one XCD's L2 (x-slice fetched once, wkv cached). R13-proven.
__global__ __launch_bounds__(256, 2) void kvattn_kernel(
    const unsigned short* __restrict__ xb,   // (8192,512) bf16
    const unsigned short* __restrict__ wkv,  // (1024,512) bf16
    const float* __restrict__ b_in,          // (1536) fp32
    const unsigned short* __restrict__ Qs,   // (32,512) bf16
    unsigned short* __restrict__ Oh)         // (8,2048,64) bf16
{
    const int g = blockIdx.x;  // 0..63  (fast dim -> XCD id = g%8)
    const int h = blockIdx.y;  // 0..7
    const int tid = threadIdx.x;
    const int w = tid >> 6, lane = tid & 63, l15 = lane & 15, l4 = lane >> 4;

    __shared__ __align__(16) unsigned short Wstage[16][512];  // 16 KB, swizzled
    __shared__ __align__(16) unsigned short K_lds[128][72];   // [node][d]
    __shared__ __align__(16) unsigned short Vt_lds[64][136];  // [d][node]
    __shared__ __align__(16) float S_lds[32][132];
    __shared__ __align__(16) unsigned short P_lds[32][136];

    // x A-fragments: wave w owns nodes w*32 .. w*32+31 (two 16-row tiles), K=512
    short8 a0[16], a1[16];
    {
        const long xrow0 = (long)(g * 128 + w * 32 + l15) * 512 + l4 * 8;
#pragma unroll
        for (int kk = 0; kk < 16; ++kk) a0[kk] = *(const short8*)(xb + xrow0 + kk * 32);
        const long xrow1 = xrow0 + 16 * 512;
#pragma unroll
        for (int kk = 0; kk < 16; ++kk) a1[kk] = *(const short8*)(xb + xrow1 + kk * 32);
    }

    // ---- KV projection: 8 chunks of 16 weight rows (0..3 = K cols, 4..7 = V cols) ----
    for (int cb = 0; cb < 8; ++cb) {
        if (cb) __syncthreads();
        const int wrow = (cb < 4) ? (h * 64 + cb * 16) : (512 + h * 64 + (cb - 4) * 16);
        // stage 16 rows (16 KB) swizzled
#pragma unroll
        for (int j = 0; j < 4; ++j) {
            int c = tid + j * 256;        // 0..1023
            int row = c >> 6;             // 0..15
            int col8 = c & 63;            // 16B unit
            *(short8*)(&Wstage[row][(col8 ^ (row & 7)) * 8]) =
                *(const short8*)(wkv + (long)(wrow + row) * 512 + col8 * 8);
        }
        __syncthreads();
        const float bias = b_in[512 + wrow + l15];
#pragma unroll
        for (int rt = 0; rt < 2; ++rt) {
            f32x4 acc = {0.f, 0.f, 0.f, 0.f};
#pragma unroll
            for (int kk = 0; kk < 16; ++kk) {
                short8 b = *(const short8*)(&Wstage[l15][((kk * 4 + l4) ^ (l15 & 7)) * 8]);
                acc = __builtin_amdgcn_mfma_f32_16x16x32_bf16(rt ? a1[kk] : a0[kk], b, acc, 0, 0, 0);
            }
            const int node0 = w * 32 + rt * 16 + l4 * 4;
            if (cb < 4) {
                const int col = cb * 16 + l15;
#pragma unroll
                for (int r = 0; r < 4; ++r) K_lds[node0 + r][col] = f2bf(acc[r] + bias);
            } else {
                const int d = (cb - 4) * 16 + l15;
#pragma unroll
                for (int r = 0; r < 4; ++r) Vt_lds[d][node0 + r] = f2bf(acc[r] + bias);
            }
        }
    }
    __syncthreads();

    // ---- S = (Q_h @ K_h^T) * 0.125 ----
    for (int lt = 0; lt < 2; ++lt) {
        const int l0 = lt * 16;
        short8 qa[2];
        qa[0] = *(const short8*)(Qs + (long)(l0 + l15) * 512 + h * 64 + l4 * 8);
        qa[1] = *(const short8*)(Qs + (long)(l0 + l15) * 512 + h * 64 + 32 + l4 * 8);
        for (int ct = 0; ct < 2; ++ct) {
            const int n0 = w * 32 + ct * 16;
            f32x4 acc = {0.f, 0.f, 0.f, 0.f};
#pragma unroll
            for (int kk = 0; kk < 2; ++kk) {
                short8 b = *(const short8*)(&K_lds[n0 + l15][kk * 32 + l4 * 8]);
                acc = __builtin_amdgcn_mfma_f32_16x16x32_bf16(qa[kk], b, acc, 0, 0, 0);
            }
#pragma unroll
            for (int r = 0; r < 4; ++r)
                S_lds[l0 + l4 * 4 + r][n0 + l15] = acc[r] * 0.125f;
        }
    }
    __syncthreads();

    // ---- row softmax over 128 nodes ----
    {
        const int row = tid >> 3;
        const int j = tid & 7;
        float vals[16];
        float m = -1e30f;
#pragma unroll
        for (int c = 0; c < 16; ++c) {
            vals[c] = S_lds[row][j + c * 8];
            m = fmaxf(m, vals[c]);
        }
#pragma unroll
        for (int s = 1; s < 8; s <<= 1) m = fmaxf(m, __shfl_xor(m, s));
        float sum = 0.f;
#pragma unroll
        for (int c = 0; c < 16; ++c) {
            vals[c] = __expf(vals[c] - m);
            sum += vals[c];
        }
#pragma unroll
        for (int s = 1; s < 8; s <<= 1) sum += __shfl_xor(sum, s);
        const float inv = 1.0f / sum;
#pragma unroll
        for (int c = 0; c < 16; ++c)
            P_lds[row][j + c * 8] = f2bf(vals[c] * inv);
    }
    __syncthreads();

    // ---- O_h = P @ V_h -> Oh[h][g*32+l][d] ----
    for (int lt = 0; lt < 2; ++lt) {
        const int l0 = lt * 16;
        const int d0 = w * 16;
        f32x4 acc = {0.f, 0.f, 0.f, 0.f};
#pragma unroll
        for (int kk = 0; kk < 4; ++kk) {
            short8 a = *(const short8*)(&P_lds[l0 + l15][kk * 32 + l4 * 8]);
            short8 b = *(const short8*)(&Vt_lds[d0 + l15][kk * 32 + l4 * 8]);
            acc = __builtin_amdgcn_mfma_f32_16x16x32_bf16(a, b, acc, 0, 0, 0);
        }
#pragma unroll
        for (int r = 0; r < 4; ++r) {
            const int l = l0 + l4 * 4 + r;
            Oh[(long)h * 131072 + (long)(g * 32 + l) * 64 + d0 + l15] = f2bf(acc[r]);
        }
    }
}

// ---------------- K3: out = Oh-gathered @ Wo^T + bo, grid (128 rows, 2 col-halves) ----------------
// R13's outproj2 with doubled parallelism: each block computes 16 rows x 256 cols.
__global__ __launch_bounds__(256, 2) void outproj2_kernel(
    const unsigned short* __restrict__ Oh, const unsigned short* __restrict__ wob,
    const float* __restrict__ bo, float* __restrict__ out)
{
    const int by = blockIdx.x;  // 0..127 (16 rows each)
    const int ch = blockIdx.y;  // 0..1 (col half)
    const int tid = threadIdx.x;
    const int w = tid >> 6, lane = tid & 63, l15 = lane & 15, l4 = lane >> 4;

    __shared__ __align__(16) unsigned short O_lds[16][520];

#pragma unroll
    for (int i = 0; i < 4; ++i) {
        int c2 = tid + i * 256;       // 16 rows x 64 chunks of 8
        int row = c2 >> 6;
        int c = c2 & 63;
        int hh = c >> 3;
        int d = (c & 7) * 8;
        *(short8*)(&O_lds[row][c * 8]) =
            *(const short8*)(Oh + (long)hh * 131072 + (long)(by * 16 + row) * 64 + d);
    }
    __syncthreads();

    short8 a[16];
#pragma unroll
    for (int kk = 0; kk < 16; ++kk)
        a[kk] = *(const short8*)(&O_lds[l15][kk * 32 + l4 * 8]);

    const int cbase = ch * 256 + w * 64;
    for (int ct = 0; ct < 4; ++ct) {
        const int col0 = cbase + ct * 16;
        f32x4 acc = {0.f, 0.f, 0.f, 0.f};
#pragma unroll
        for (int kk = 0; kk < 16; ++kk) {
            short8 b = *(const short8*)(wob + (long)(col0 + l15) * 512 + kk * 32 + l4 * 8);
            acc = __builtin_amdgcn_mfma_f32_16x16x32_bf16(a[kk], b, acc, 0, 0, 0);
        }
        const float bias = bo[col0 + l15];
#pragma unroll
        for (int r = 0; r < 4; ++r)
            out[(long)(by * 16 + l4 * 4 + r) * 512 + col0 + l15] = acc[r] + bias;
    }
}

// ================= fp32 fallback (tiny ws) =================
template<bool F32>
__device__ void attn_body(const void* x, const void* w_in, const float* b_in,
                          const void* aggrs, float* O) {
    const int h = blockIdx.x;
    const int g = blockIdx.y;
    const int tid = threadIdx.x;
    const int w = tid >> 6, lane = tid & 63, l15 = lane & 15, l4 = lane >> 4;

    __shared__ __align__(16) unsigned short Q_lds[32][72];
    __shared__ __align__(16) unsigned short K_lds[128][72];
    __shared__ __align__(16) unsigned short Vt_lds[64][136];
    __shared__ __align__(16) float S_lds[32][132];
    __shared__ __align__(16) unsigned short P_lds[32][136];

    const long xg = (long)g * 128 * 512;
    const long WqO = (long)(h * 64) * 512;
    const long WkO = (long)(512 + h * 64) * 512;
    const long WvO = (long)(1024 + h * 64) * 512;

    {
        const int d0 = w * 16;
        const float bq = b_in[h * 64 + d0 + l15];
        for (int rt = 0; rt < 2; ++rt) {
            f32x4 acc = {0.f, 0.f, 0.f, 0.f};
#pragma unroll
            for (int kk = 0; kk < 16; ++kk) {
                short8 a = load8<F32>(aggrs, (long)(rt * 16 + l15) * 512 + l4 * 8 + kk * 32);
                short8 b = load8<F32>(w_in, WqO + (long)(d0 + l15) * 512 + l4 * 8 + kk * 32);
                acc = __builtin_amdgcn_mfma_f32_16x16x32_bf16(a, b, acc, 0, 0, 0);
            }
#pragma unroll
            for (int r = 0; r < 4; ++r)
                Q_lds[rt * 16 + l4 * 4 + r][d0 + l15] = f2bf(acc[r] + bq);
        }
    }
    for (int rt = 0; rt < 2; ++rt) {
        const int n0 = w * 32 + rt * 16;
        short8 a[16];
#pragma unroll
        for (int kk = 0; kk < 16; ++kk)
            a[kk] = load8<F32>(x, xg + (long)(n0 + l15) * 512 + l4 * 8 + kk * 32);
        for (int ct = 0; ct < 4; ++ct) {
            const int d0 = ct * 16;
            f32x4 accK = {0.f, 0.f, 0.f, 0.f};
            f32x4 accV = {0.f, 0.f, 0.f, 0.f};
#pragma unroll
            for (int kk = 0; kk < 16; ++kk) {
                short8 bk = load8<F32>(w_in, WkO + (long)(d0 + l15) * 512 + l4 * 8 + kk * 32);
                short8 bv = load8<F32>(w_in, WvO + (long)(d0 + l15) * 512 + l4 * 8 + kk * 32);
                accK = __builtin_amdgcn_mfma_f32_16x16x32_bf16(a[kk], bk, accK, 0, 0, 0);
                accV = __builtin_amdgcn_mfma_f32_16x16x32_bf16(a[kk], bv, accV, 0, 0, 0);
            }
            const float biasK = b_in[512 + h * 64 + d0 + l15];
            const float biasV = b_in[1024 + h * 64 + d0 + l15];
#pragma unroll
            for (int r = 0; r < 4; ++r) {
                const int row = n0 + l4 * 4 + r;
                const int col = d0 + l15;
                K_lds[row][col] = f2bf(accK[r] + biasK);
                Vt_lds[col][row] = f2bf(accV[r] + biasV);
            }
        }
    }
    __syncthreads();
    for (int lt = 0; lt < 2; ++lt) {
        const int l0 = lt * 16;
        short8 qa[2];
        qa[0] = *(const short8*)(&Q_lds[l0 + l15][l4 * 8]);
        qa[1] = *(const short8*)(&Q_lds[l0 + l15][32 + l4 * 8]);
        for (int ct = 0; ct < 2; ++ct) {
            const int n0 = w * 32 + ct * 16;
            f32x4 acc = {0.f, 0.f, 0.f, 0.f};
#pragma unroll
            for (int kk = 0; kk < 2; ++kk) {
                short8 b = *(const short8*)(&K_lds[n0 + l15][kk * 32 + l4 * 8]);
                acc = __builtin_amdgcn_mfma_f32_16x16x32_bf16(qa[kk], b, acc, 0, 0, 0);
            }
#pragma unroll
            for (int r = 0; r < 4; ++r)
                S_lds[l0 + l4 * 4 + r][n0 + l15] = acc[r] * 0.125f;
        }
    }
    __syncthreads();
    {
        const int row = tid >> 3;
        const int j = tid & 7;
        float vals[16];
        float m = -1e30f;
#pragma unroll
        for (int c = 0; c < 16; ++c) {
            vals[c] = S_lds[row][j + c * 8];
            m = fmaxf(m, vals[c]);
        }
#pragma unroll
        for (int s = 1; s < 8; s <<= 1) m = fmaxf(m, __shfl_xor(m, s));
        float sum = 0.f;
#pragma unroll
        for (int c = 0; c < 16; ++c) {
            vals[c] = __expf(vals[c] - m);
            sum += vals[c];
        }
#pragma unroll
        for (int s = 1; s < 8; s <<= 1) sum += __shfl_xor(sum, s);
        const float inv = 1.0f / sum;
#pragma unroll
        for (int c = 0; c < 16; ++c)
            P_lds[row][j + c * 8] = f2bf(vals[c] * inv);
    }
    __syncthreads();
    for (int lt = 0; lt < 2; ++lt) {
        const int l0 = lt * 16;
        const int d0 = w * 16;
        f32x4 acc = {0.f, 0.f, 0.f, 0.f};
#pragma unroll
        for (int kk = 0; kk < 4; ++kk) {
            short8 a = *(const short8*)(&P_lds[l0 + l15][kk * 32 + l4 * 8]);
            short8 b = *(const short8*)(&Vt_lds[d0 + l15][kk * 32 + l4 * 8]);
            acc = __builtin_amdgcn_mfma_f32_16x16x32_bf16(a, b, acc, 0, 0, 0);
        }
#pragma unroll
        for (int r = 0; r < 4; ++r) {
            const int l = l0 + l4 * 4 + r;
            O[(long)(g * 32 + l) * 512 + h * 64 + d0 + l15] = acc[r];
        }
    }
}
__global__ __launch_bounds__(256) void attn_f32(const float* x, const float* w_in,
                                                const float* b_in, const float* aggrs,
                                                float* O) {
    attn_body<true>(x, w_in, b_in, aggrs, O);
}

template<bool F32>
__device__ void outproj_body(float* Out, const void* Wo, const float* bo) {
    const int by = blockIdx.x;
    const int tid = threadIdx.x;
    const int w = tid >> 6, lane = tid & 63, l15 = lane & 15, l4 = lane >> 4;

    __shared__ __align__(16) unsigned short O_lds[16][520];

#pragma unroll
    for (int i = 0; i < 4; ++i) {
        int c2 = tid + i * 256;
        int row = c2 >> 6;
        int col = (c2 & 63) * 8;
        const float* src = Out + (long)(by * 16 + row) * 512 + col;
        f32x4 a = *(const f32x4*)src;
        f32x4 b = *(const f32x4*)(src + 4);
        short8 v;
#pragma unroll
        for (int j = 0; j < 4; ++j) { v[j] = (short)f2bf(a[j]); v[4 + j] = (short)f2bf(b[j]); }
        *(short8*)(&O_lds[row][col]) = v;
    }
    __syncthreads();

    short8 a[16];
#pragma unroll
    for (int kk = 0; kk < 16; ++kk)
        a[kk] = *(const short8*)(&O_lds[l15][kk * 32 + l4 * 8]);

    const int cbase = w * 128;
    for (int ct = 0; ct < 8; ++ct) {
        const int col0 = cbase + ct * 16;
        f32x4 acc = {0.f, 0.f, 0.f, 0.f};
#pragma unroll
        for (int kk = 0; kk < 16; ++kk) {
            short8 b = load8<F32>(Wo, (long)(col0 + l15) * 512 + l4 * 8 + kk * 32);
            acc = __builtin_amdgcn_mfma_f32_16x16x32_bf16(a[kk], b, acc, 0, 0, 0);
        }
        const float bias = bo[col0 + l15];
#pragma unroll
        for (int r = 0; r < 4; ++r)
            Out[(long)(by * 16 + l4 * 4 + r) * 512 + col0 + l15] = acc[r] + bias;
    }
}
__global__ __launch_bounds__(256) void outproj_f32(float* Out, const float* Wo,
                                                   const float* bo) {
    outproj_body<true>(Out, Wo, bo);
}

extern "C" void kernel_launch(void* const* d_in, const int* in_sizes, int n_in,
                              void* d_out, int out_size, void* d_ws, size_t ws_size,
                              hipStream_t stream) {
    // Size-based input dispatch — all 7 element counts distinct -> robust to any ordering.
    const int want[7] = {64 * 128 * 512, 64 * 128, 32 * 512, 1536 * 512, 1536, 512 * 512, 512};
    const void* p[7] = {0, 0, 0, 0, 0, 0, 0};
    for (int i = 0; i < n_in && i < 16; ++i)
        for (int j = 0; j < 7; ++j)
            if (in_sizes[i] == want[j] && p[j] == 0) { p[j] = d_in[i]; break; }

    const float* x     = (const float*)p[0];
    const float* aggrs = (const float*)p[2];
    const float* w_in  = (const float*)p[3];
    const float* b_in  = (const float*)p[4];
    const float* Wo    = (const float*)p[5];
    const float* bo    = (const float*)p[6];
    float* out = (float*)d_out;  // (2048,512) fp32

    // ws layout (ushort units)
    const size_t WKV = 0;          // (1024,512) bf16
    const size_t WOB = 524288;     // (512,512) bf16
    const size_t QSo = 786432;     // (32,512) bf16
    const size_t XB  = 802816;     // (8192,512) bf16
    const size_t OHo = 4997120;    // (8,2048,64) bf16
    const size_t END = 6045696;    // 12.1 MB (ws proven >= 29.4 MB)

    unsigned short* ws = (unsigned short*)d_ws;
    if (ws_size >= END * 2) {
        prep_kernel<<<dim3(2440), dim3(256), 0, stream>>>(w_in, Wo, aggrs, b_in, x,
                                                          ws + WKV, ws + WOB, ws + QSo,
                                                          ws + XB);
        kvattn_kernel<<<dim3(64, 8), dim3(256), 0, stream>>>(ws + XB, ws + WKV, b_in,
                                                             ws + QSo, ws + OHo);
        outproj2_kernel<<<dim3(128, 2), dim3(256), 0, stream>>>(ws + OHo, ws + WOB, bo, out);
    } else {
        attn_f32<<<dim3(8, 64), dim3(256), 0, stream>>>(x, w_in, b_in, aggrs, out);
        outproj_f32<<<dim3(128), dim3(256), 0, stream>>>(out, Wo, bo);
    }
}